// Round 2
// baseline (249.057 us; speedup 1.0000x reference)
//
#include <hip/hip_runtime.h>

// Problem constants (B=16, T=512, N=2048, U=64) — all inputs/outputs FP32.
#define N_DIM 2048
#define U_DIM 64
#define M_DIM 8192   // B*T
#define K_DIM 2048   // = N

typedef __bf16 bf16x8 __attribute__((ext_vector_type(8)));
typedef float  floatx4 __attribute__((ext_vector_type(4)));
typedef unsigned short ushort8 __attribute__((ext_vector_type(8)));

#define AS1 __attribute__((address_space(1)))
#define AS3 __attribute__((address_space(3)))

__device__ __forceinline__ unsigned short f_to_bf16_rne(float f) {
    unsigned int x;
    __builtin_memcpy(&x, &f, 4);
    x += 0x7fffu + ((x >> 16) & 1u);
    return (unsigned short)(x >> 16);
}

// ---------------------------------------------------------------------------
// Kernel 1: wbar[k] = mean_i W[i,k]  (fp32), bmean = mean(b)
// ---------------------------------------------------------------------------
__global__ __launch_bounds__(256) void prep_kernel(
    const float* __restrict__ W,   // [U_DIM, N_DIM]
    const float* __restrict__ b,   // [U_DIM]
    float* __restrict__ wbar,      // [N_DIM]
    float* __restrict__ bmean) {   // [1]
    int k = blockIdx.x * 256 + threadIdx.x;
    float s = 0.f;
#pragma unroll
    for (int i = 0; i < U_DIM; ++i) s += W[i * N_DIM + k];
    wbar[k] = s * (1.f / U_DIM);

    if (blockIdx.x == 0 && threadIdx.x < 64) {
        float v = b[threadIdx.x];
#pragma unroll
        for (int off = 32; off > 0; off >>= 1) v += __shfl_down(v, off);
        if (threadIdx.x == 0) bmean[0] = v * (1.f / U_DIM);
    }
}

// ---------------------------------------------------------------------------
// Kernel 2: weff[j,k] = bf16( Adj[j,k] * wbar[k] )   (4M elements, x8 vec)
// ---------------------------------------------------------------------------
__global__ __launch_bounds__(256) void weff_kernel(
    const float* __restrict__ Adj,        // [N,N] fp32
    const float* __restrict__ wbar,       // [N]   fp32
    unsigned short* __restrict__ weff) {  // [N,N] bf16 bits
    long long idx = ((long long)blockIdx.x * 256 + threadIdx.x) * 8;
    int k = (int)(idx & (N_DIM - 1));
    floatx4 a0 = *(const floatx4*)(Adj + idx);
    floatx4 a1 = *(const floatx4*)(Adj + idx + 4);
    floatx4 w0 = *(const floatx4*)(wbar + k);
    floatx4 w1 = *(const floatx4*)(wbar + k + 4);
    ushort8 ov;
#pragma unroll
    for (int j = 0; j < 4; ++j) {
        ov[j]     = f_to_bf16_rne(a0[j] * w0[j]);
        ov[j + 4] = f_to_bf16_rne(a1[j] * w1[j]);
    }
    *(ushort8*)(weff + idx) = ov;
}

// ---------------------------------------------------------------------------
// Kernel 3: x (fp32) -> bf16 bits, 8 elems/thread. One block = one 2048 row.
// ---------------------------------------------------------------------------
__global__ __launch_bounds__(256) void convx_kernel(
    const float* __restrict__ x,
    unsigned short* __restrict__ xbf) {
    long long idx = ((long long)blockIdx.x * 256 + threadIdx.x) * 8;
    floatx4 a0 = *(const floatx4*)(x + idx);
    floatx4 a1 = *(const floatx4*)(x + idx + 4);
    ushort8 ov;
#pragma unroll
    for (int j = 0; j < 4; ++j) {
        ov[j]     = f_to_bf16_rne(a0[j]);
        ov[j + 4] = f_to_bf16_rne(a1[j]);
    }
    *(ushort8*)(xbf + idx) = ov;
}

// ---------------------------------------------------------------------------
// Kernel 4: C[m,j] = sum_k A[m,k]*Bt[j,k] + bmean   (bf16 in, fp32 acc/out)
// 128x128 tile, BK=32, 256 threads (4 waves), each wave 64x64 via 4x4 MFMAs.
// global_load_lds width=16 staging (wave-uniform base + lane*16 contiguous).
// ---------------------------------------------------------------------------
#define BM 128
#define BN 128
#define BK 32

__global__ __launch_bounds__(256) void gemm_bt_kernel(
    const unsigned short* __restrict__ A,    // [rows, K_DIM] bf16 bits (xbf)
    const unsigned short* __restrict__ Bt,   // [N_DIM, K_DIM] bf16 bits (weff)
    const float* __restrict__ bmeanp,
    float* __restrict__ C) {                 // [rows, N_DIM] fp32
    __shared__ __align__(16) unsigned short sA[BM * BK];
    __shared__ __align__(16) unsigned short sB[BN * BK];

    const int tid  = threadIdx.x;
    const int w    = tid >> 6;    // wave 0..3
    const int lane = tid & 63;
    const int tile_m = blockIdx.y * BM;
    const int tile_n = blockIdx.x * BN;

    const float bmean = bmeanp[0];

    // staging: wave w stages chunks (w*2) and (w*2+1) of A and B.
    // Chunk c covers rows c*16..c*16+15 (row = 32 bf16 = 64 B = 4 lanes x 16 B).
    const int srow = lane >> 2;        // 0..15 within chunk
    const int scol = (lane & 3) * 8;   // element offset within row
    const unsigned short* gA0 = A + (size_t)(tile_m + (w * 2 + 0) * 16 + srow) * K_DIM + scol;
    const unsigned short* gA1 = A + (size_t)(tile_m + (w * 2 + 1) * 16 + srow) * K_DIM + scol;
    const unsigned short* gB0 = Bt + (size_t)(tile_n + (w * 2 + 0) * 16 + srow) * K_DIM + scol;
    const unsigned short* gB1 = Bt + (size_t)(tile_n + (w * 2 + 1) * 16 + srow) * K_DIM + scol;
    unsigned short* lA0 = &sA[(w * 2 + 0) * 16 * BK];
    unsigned short* lA1 = &sA[(w * 2 + 1) * 16 * BK];
    unsigned short* lB0 = &sB[(w * 2 + 0) * 16 * BK];
    unsigned short* lB1 = &sB[(w * 2 + 1) * 16 * BK];

    // fragment read offsets (elements) in LDS
    const int wrow = (w >> 1) * 64;    // wave's 64-row block in tile
    const int wcol = (w & 1) * 64;     // wave's 64-col block in tile
    const int fr = lane & 15;          // m (for A) / n (for B)
    const int fq = lane >> 4;          // quad -> k = fq*8 + j
    int aoff[4], boff[4];
#pragma unroll
    for (int i = 0; i < 4; ++i) {
        aoff[i] = (wrow + i * 16 + fr) * BK + fq * 8;
        boff[i] = (wcol + i * 16 + fr) * BK + fq * 8;
    }

    floatx4 acc[4][4];
#pragma unroll
    for (int mi = 0; mi < 4; ++mi)
#pragma unroll
        for (int ni = 0; ni < 4; ++ni) acc[mi][ni] = (floatx4){0.f, 0.f, 0.f, 0.f};

    for (int k0 = 0; k0 < K_DIM; k0 += BK) {
        __syncthreads();  // prev iteration's LDS reads done before overwrite
        __builtin_amdgcn_global_load_lds((const AS1 void*)(gA0 + k0), (AS3 void*)lA0, 16, 0, 0);
        __builtin_amdgcn_global_load_lds((const AS1 void*)(gA1 + k0), (AS3 void*)lA1, 16, 0, 0);
        __builtin_amdgcn_global_load_lds((const AS1 void*)(gB0 + k0), (AS3 void*)lB0, 16, 0, 0);
        __builtin_amdgcn_global_load_lds((const AS1 void*)(gB1 + k0), (AS3 void*)lB1, 16, 0, 0);
        __syncthreads();  // vmcnt drained before barrier

        bf16x8 af[4], bf[4];
#pragma unroll
        for (int i = 0; i < 4; ++i) {
            af[i] = *(const bf16x8*)&sA[aoff[i]];
            bf[i] = *(const bf16x8*)&sB[boff[i]];
        }
#pragma unroll
        for (int mi = 0; mi < 4; ++mi)
#pragma unroll
            for (int ni = 0; ni < 4; ++ni)
                acc[mi][ni] = __builtin_amdgcn_mfma_f32_16x16x32_bf16(
                    af[mi], bf[ni], acc[mi][ni], 0, 0, 0);
    }

    // Epilogue: C/D layout col = lane&15, row = (lane>>4)*4 + reg  [m89/m91]
    const int crow = tile_m + wrow + fq * 4;
    const int ccol = tile_n + wcol + fr;
#pragma unroll
    for (int mi = 0; mi < 4; ++mi)
#pragma unroll
        for (int ni = 0; ni < 4; ++ni)
#pragma unroll
            for (int r = 0; r < 4; ++r) {
                int gm = crow + mi * 16 + r;
                int gn = ccol + ni * 16;
                C[(size_t)gm * N_DIM + gn] = acc[mi][ni][r] + bmean;
            }
}

// ---------------------------------------------------------------------------
extern "C" void kernel_launch(void* const* d_in, const int* in_sizes, int n_in,
                              void* d_out, int out_size, void* d_ws, size_t ws_size,
                              hipStream_t stream) {
    (void)in_sizes; (void)n_in; (void)out_size;
    const float* x   = (const float*)d_in[0];  // [16,512,2048]
    const float* Adj = (const float*)d_in[1];  // [2048,2048]
    const float* W   = (const float*)d_in[2];  // [64,2048]
    const float* b   = (const float*)d_in[3];  // [64]
    float* out = (float*)d_out;                // [16,512,2048] fp32

    // ws layout: wbar fp32 @0 (8 KB) | bmean @8192 | weff bf16 @16384 (8.39 MB)
    //            | xbf bf16 chunk @16384+weff_bytes (up to 33.6 MB)
    char* ws = (char*)d_ws;
    float* wbar  = (float*)ws;
    float* bmean = (float*)(ws + 8192);
    unsigned short* weff = (unsigned short*)(ws + 16384);
    const size_t weff_bytes = (size_t)N_DIM * N_DIM * 2;
    const size_t xbf_off = 16384 + weff_bytes;
    unsigned short* xbf = (unsigned short*)(ws + xbf_off);

    // M-chunking so xbf fits in whatever ws_size we were given (deterministic
    // per-session -> graph-capture safe).
    size_t avail = (ws_size > xbf_off) ? (ws_size - xbf_off) : 0;
    long long max_rows = (long long)(avail / ((size_t)K_DIM * 2)) / BM * BM;
    if (max_rows < BM) max_rows = BM;      // best effort if ws is tiny
    if (max_rows > M_DIM) max_rows = M_DIM;

    prep_kernel<<<N_DIM / 256, 256, 0, stream>>>(W, b, wbar, bmean);
    weff_kernel<<<(int)(((size_t)N_DIM * N_DIM / 8) / 256), 256, 0, stream>>>(Adj, wbar, weff);

    for (long long m0 = 0; m0 < M_DIM; m0 += max_rows) {
        long long rows = (M_DIM - m0 < max_rows) ? (M_DIM - m0) : max_rows;
        // convx: one block per 2048-element row
        convx_kernel<<<(int)rows, 256, 0, stream>>>(x + m0 * K_DIM, xbf);
        dim3 grid(N_DIM / BN, (int)(rows / BM));
        gemm_bt_kernel<<<grid, 256, 0, stream>>>(xbf, weff, bmean, out + m0 * (size_t)N_DIM);
    }
}